// Round 23
// baseline (243.736 us; speedup 1.0000x reference)
//
#include <hip/hip_runtime.h>
#include <hip/hip_bf16.h>
#include <stdint.h>

typedef unsigned short u16;
typedef __attribute__((ext_vector_type(8))) short short8;   // 8 bf16 = 4 VGPR
typedef __attribute__((ext_vector_type(4))) short short4v;  // 8B
typedef __attribute__((ext_vector_type(4))) float f32x4;
typedef __attribute__((ext_vector_type(16))) float f32x16;
typedef __attribute__((ext_vector_type(2))) unsigned int uint2v;
typedef __attribute__((ext_vector_type(4))) unsigned int uint4v;

#define DEV static __device__ __forceinline__

DEV u16 f2bf(float f) {
  union { float f; unsigned u; } x; x.f = f;
  unsigned r = x.u + 0x7FFFu + ((x.u >> 16) & 1u);
  return (u16)(r >> 16);
}

DEV unsigned cvtpk_bf16(float a, float b) {  // mem order: {bf16(a), bf16(b)} (RNE)
  unsigned r;
  asm("v_cvt_pk_bf16_f32 %0, %1, %2" : "=v"(r) : "v"(a), "v"(b));
  return r;
}

// swaps a.hi32lanes <-> b.lo32lanes
DEV void pl32swap(unsigned& a, unsigned& b) {
  asm("v_permlane32_swap_b32 %0, %1" : "+v"(a), "+v"(b));
}

DEV void gld_lds16(const void* g, void* l) {
  __builtin_amdgcn_global_load_lds(
      (const __attribute__((address_space(1))) unsigned int*)(g),
      (__attribute__((address_space(3))) unsigned int*)(l),
      16, 0, 0);
}

// ---------------- merged fp32->bf16 converts + delta prescale ----------------
__global__ void cvt_all(const float* __restrict__ q, const float* __restrict__ k,
                        const float* __restrict__ v, const float* __restrict__ Wq,
                        const float* __restrict__ Wk, const float* __restrict__ Wv,
                        const float* __restrict__ Wo, const float* __restrict__ delta,
                        u16* __restrict__ qbf, u16* __restrict__ kbf,
                        u16* __restrict__ vbf, u16* __restrict__ wbase,
                        float* __restrict__ dl2g) {
  int tid = threadIdx.x;
  int y = blockIdx.y;
  if (y < 3) {
    int i = blockIdx.x * 256 + tid;
    const float* in = (y == 0) ? q : (y == 1) ? k : v;
    u16* out = (y == 0) ? qbf : (y == 1) ? kbf : vbf;
    float4 x = ((const float4*)in)[i];
    uint2v o;
    o[0] = cvtpk_bf16(x.x, x.y);
    o[1] = cvtpk_bf16(x.z, x.w);
    ((uint2v*)out)[i] = o;
    return;
  }
  int j = blockIdx.x * 256 + tid;
  if (j < 1048576) {  // weights: w uniform per block (262144 % 256 == 0)
    int w = j >> 18, jj = j & 262143;
    const float* in = (w == 0) ? Wq : (w == 1) ? Wk : (w == 2) ? Wv : Wo;
    u16* out = wbase + ((size_t)w << 20);
    float4 x = ((const float4*)in)[jj];
    uint2v o;
    o[0] = cvtpk_bf16(x.x, x.y);
    o[1] = cvtpk_bf16(x.z, x.w);
    ((uint2v*)out)[jj] = o;
  } else if (j < 1048576 + 2048) {  // delta prescale
    int jj = j - 1048576;
    constexpr float C = 0.125f * 1.44269504f;
    float4 x = ((const float4*)delta)[jj];
    f32x4 o = {x.x * C, x.y * C, x.z * C, x.w * C};
    ((f32x4*)dl2g)[jj] = o;
  }
}

// ---------------- fused QKV GEMM over stacked A (24576 x 1024) ----------------
// Q output pre-scaled by tau[b]*0.125*log2e. LDS-bounce epilogue (r22).
__global__ __launch_bounds__(256, 2)
void gemm_qkv(const u16* __restrict__ A, const u16* __restrict__ W,
              const float* __restrict__ bq, const float* __restrict__ bk,
              const float* __restrict__ bv, const float* __restrict__ tau,
              u16* __restrict__ qhb, u16* __restrict__ khb, u16* __restrict__ vtb) {
  constexpr int Nn = 1024, Kn = 1024;
  constexpr int BM = 128, BN = 128, BK = 64;
  __shared__ __align__(16) u16 smem[17408];
  u16* As = smem;
  u16* Bs = smem + 8192;
  constexpr int nbn = Nn / BN;            // 8
  constexpr int nwg = (24576 / BM) * nbn; // 1536
  int bid = blockIdx.x;
  int swz = (bid & 7) * (nwg >> 3) + (bid >> 3);
  int bm = (swz / nbn) * BM;
  int bn = (swz % nbn) * BN;
  int mat = bm >> 13;          // 0=Q 1=K 2=V
  int bml = bm & 8191;
  int tid = threadIdx.x;
  int lane = tid & 63, w = tid >> 6;
  int l15 = lane & 15, l4 = lane >> 4;
  int wm = (w >> 1) * 64, wn = (w & 1) * 64;
  int swl = (w << 6);

  f32x4 acc[4][4];
#pragma unroll
  for (int i = 0; i < 4; ++i)
#pragma unroll
    for (int j = 0; j < 4; ++j) acc[i][j] = (f32x4){0.f, 0.f, 0.f, 0.f};

  const u16* Ag = A + (size_t)bm * Kn;
  const u16* Bg = W + ((size_t)mat << 20) + (size_t)bn * Kn;

  for (int kt = 0; kt < Kn / BK; ++kt) {
    int k0 = kt * BK;
#pragma unroll
    for (int j = 0; j < 4; ++j) {
      int flat = j * 256 + tid;
      int row = flat >> 3, u = flat & 7;
      int gu = u ^ (row & 7);
      gld_lds16(Ag + (size_t)row * Kn + k0 + gu * 8, &As[(j * 256 + swl) * 8]);
    }
#pragma unroll
    for (int j = 0; j < 4; ++j) {
      int flat = j * 256 + tid;
      int row = flat >> 3, u = flat & 7;
      int gu = u ^ (row & 7);
      gld_lds16(Bg + (size_t)row * Kn + k0 + gu * 8, &Bs[(j * 256 + swl) * 8]);
    }
    __syncthreads();
#pragma unroll
    for (int ks = 0; ks < 2; ++ks) {
      short8 af[4], bfr[4];
#pragma unroll
      for (int i = 0; i < 4; ++i) {
        int ra = wm + i * 16 + l15;
        int ua = (ks * 4 + l4) ^ (ra & 7);
        af[i] = *(const short8*)&As[ra * 64 + ua * 8];
        int rb = wn + i * 16 + l15;
        int ub = (ks * 4 + l4) ^ (rb & 7);
        bfr[i] = *(const short8*)&Bs[rb * 64 + ub * 8];
      }
#pragma unroll
      for (int mi = 0; mi < 4; ++mi)
#pragma unroll
        for (int ni = 0; ni < 4; ++ni)
          acc[mi][ni] = __builtin_amdgcn_mfma_f32_16x16x32_bf16(af[mi], bfr[ni], acc[mi][ni], 0, 0, 0);
    }
    __syncthreads();
  }

  const float* bias = (mat == 0) ? bq : (mat == 1) ? bk : bv;
  float st2b = (mat == 0) ? tau[bml >> 11] * (0.125f * 1.44269504f) : 1.f;

  if (mat < 2) {
    u16* oQK = (mat == 0) ? qhb : khb;
#pragma unroll
    for (int ni = 0; ni < 4; ++ni) {
      int nl = wn + ni * 16 + l15;
      float bvl = bias[bn + nl];
#pragma unroll
      for (int mi = 0; mi < 4; ++mi) {
        int ml = wm + mi * 16 + l4 * 4;
        unsigned r0 = cvtpk_bf16((acc[mi][ni][0] + bvl) * st2b, (acc[mi][ni][1] + bvl) * st2b);
        unsigned r1 = cvtpk_bf16((acc[mi][ni][2] + bvl) * st2b, (acc[mi][ni][3] + bvl) * st2b);
        smem[(ml + 0) * 136 + nl] = (u16)r0;
        smem[(ml + 1) * 136 + nl] = (u16)(r0 >> 16);
        smem[(ml + 2) * 136 + nl] = (u16)r1;
        smem[(ml + 3) * 136 + nl] = (u16)(r1 >> 16);
      }
    }
    __syncthreads();
#pragma unroll
    for (int r = 0; r < 8; ++r) {
      int ml = r * 16 + (tid >> 4), seg = tid & 15;
      uint4v val = *(const uint4v*)&smem[ml * 136 + seg * 8];
      int m = bml + ml;
      int bb = m >> 11, l = m & 2047;
      int n = bn + seg * 8;
      int h = n >> 6, e = n & 63;
      *(uint4v*)&oQK[(((size_t)bb * 16 + h) * 2048 + l) * 64 + e] = val;
    }
  } else {
    // V: LDS transposed [n_local][m_local]; j gives 4 consecutive m -> b64 writes
#pragma unroll
    for (int ni = 0; ni < 4; ++ni) {
      int nl = wn + ni * 16 + l15;
      float bvl = bias[bn + nl];
#pragma unroll
      for (int mi = 0; mi < 4; ++mi) {
        int ml = wm + mi * 16 + l4 * 4;
        uint2v pk;
        pk[0] = cvtpk_bf16(acc[mi][ni][0] + bvl, acc[mi][ni][1] + bvl);
        pk[1] = cvtpk_bf16(acc[mi][ni][2] + bvl, acc[mi][ni][3] + bvl);
        *(uint2v*)&smem[nl * 136 + ml] = pk;
      }
    }
    __syncthreads();
#pragma unroll
    for (int r = 0; r < 8; ++r) {
      int nl = r * 16 + (tid >> 4), seg = tid & 15;
      uint4v val = *(const uint4v*)&smem[nl * 136 + seg * 8];
      int n = bn + nl;
      int h = n >> 6, e = n & 63;
      int bb = bml >> 11, s0 = (bml & 2047) + seg * 8;
      *(uint4v*)&vtb[(((size_t)bb * 16 + h) * 64 + e) * 2048 + s0] = val;
    }
  }
}

// ---------------- output GEMM: C = A(M,K) * Wo^T + bo, f32 out ----------------
__global__ __launch_bounds__(256, 2)
void gemm_out(const u16* __restrict__ A, const u16* __restrict__ Bt,
              const float* __restrict__ bias, float* __restrict__ out) {
  constexpr int Nn = 1024, Kn = 1024;
  constexpr int BM = 128, BN = 128, BK = 64;
  __shared__ __align__(16) u16 As[BM * BK];
  __shared__ __align__(16) u16 Bs[BN * BK];
  constexpr int nbn = Nn / BN;            // 8
  constexpr int nwg = (8192 / BM) * nbn;  // 512
  int bid = blockIdx.x;
  int swz = (bid & 7) * (nwg >> 3) + (bid >> 3);
  int bm = (swz / nbn) * BM;
  int bn = (swz % nbn) * BN;
  int tid = threadIdx.x;
  int lane = tid & 63, w = tid >> 6;
  int l15 = lane & 15, l4 = lane >> 4;
  int wm = (w >> 1) * 64, wn = (w & 1) * 64;
  int swl = (w << 6);

  f32x4 acc[4][4];
#pragma unroll
  for (int i = 0; i < 4; ++i)
#pragma unroll
    for (int j = 0; j < 4; ++j) acc[i][j] = (f32x4){0.f, 0.f, 0.f, 0.f};

  const u16* Ag = A + (size_t)bm * Kn;
  const u16* Bg = Bt + (size_t)bn * Kn;

  for (int kt = 0; kt < Kn / BK; ++kt) {
    int k0 = kt * BK;
#pragma unroll
    for (int j = 0; j < 4; ++j) {
      int flat = j * 256 + tid;
      int row = flat >> 3, u = flat & 7;
      int gu = u ^ (row & 7);
      gld_lds16(Ag + (size_t)row * Kn + k0 + gu * 8, &As[(j * 256 + swl) * 8]);
    }
#pragma unroll
    for (int j = 0; j < 4; ++j) {
      int flat = j * 256 + tid;
      int row = flat >> 3, u = flat & 7;
      int gu = u ^ (row & 7);
      gld_lds16(Bg + (size_t)row * Kn + k0 + gu * 8, &Bs[(j * 256 + swl) * 8]);
    }
    __syncthreads();
#pragma unroll
    for (int ks = 0; ks < 2; ++ks) {
      short8 af[4], bfr[4];
#pragma unroll
      for (int i = 0; i < 4; ++i) {
        int ra = wm + i * 16 + l15;
        int ua = (ks * 4 + l4) ^ (ra & 7);
        af[i] = *(const short8*)&As[ra * 64 + ua * 8];
        int rb = wn + i * 16 + l15;
        int ub = (ks * 4 + l4) ^ (rb & 7);
        bfr[i] = *(const short8*)&Bs[rb * 64 + ub * 8];
      }
#pragma unroll
      for (int mi = 0; mi < 4; ++mi)
#pragma unroll
        for (int ni = 0; ni < 4; ++ni)
          acc[mi][ni] = __builtin_amdgcn_mfma_f32_16x16x32_bf16(af[mi], bfr[ni], acc[mi][ni], 0, 0, 0);
    }
    __syncthreads();
  }

#pragma unroll
  for (int ni = 0; ni < 4; ++ni) {
    int n = bn + wn + ni * 16 + l15;
    float bvl = bias[n];
#pragma unroll
    for (int mi = 0; mi < 4; ++mi) {
      int m0 = bm + wm + mi * 16 + l4 * 4;
#pragma unroll
      for (int j = 0; j < 4; ++j)
        out[(size_t)(m0 + j) * Nn + n] = acc[mi][ni][j] + bvl;
    }
  }
}

// softmax + pack for one 32-s x 32-q subtile: sc already = logits in log2
// domain (st2 folded into Q, delta folded into MFMA C-init).
DEV float softpack(const f32x16 sc, short8& f0, short8& f1) {
  float pe[16];
#pragma unroll
  for (int i = 0; i < 16; ++i) pe[i] = __builtin_amdgcn_exp2f(sc[i]);
  float ps = 0.f;
#pragma unroll
  for (int i = 0; i < 16; i += 4) ps += (pe[i] + pe[i + 1]) + (pe[i + 2] + pe[i + 3]);
  unsigned a0 = cvtpk_bf16(pe[0], pe[1]), a1 = cvtpk_bf16(pe[2], pe[3]);
  unsigned b0 = cvtpk_bf16(pe[4], pe[5]), b1 = cvtpk_bf16(pe[6], pe[7]);
  pl32swap(a0, b0);
  pl32swap(a1, b1);
  f0 = __builtin_bit_cast(short8, (uint4v){a0, a1, b0, b1});
  unsigned c0 = cvtpk_bf16(pe[8], pe[9]), c1 = cvtpk_bf16(pe[10], pe[11]);
  unsigned d0 = cvtpk_bf16(pe[12], pe[13]), d1 = cvtpk_bf16(pe[14], pe[15]);
  pl32swap(c0, d0);
  pl32swap(c1, d1);
  f1 = __builtin_bit_cast(short8, (uint4v){c0, c1, d0, d1});
  return ps;
}

// one 64-s tile: QK (A,B interleaved), softpack, PV. Pure-register + LDS reads.
DEV void tile_compute(const char* KsB, const char* VsB, const float* dl,
                      int rb0, int rb1, int rb2, int rb3, int hi,
                      const short8 (&qfA)[4], const short8 (&qfB)[4],
                      f32x16& oaA0, f32x16& oaA1, f32x16& oaB0, f32x16& oaB1,
                      float& lA, float& lB) {
#pragma unroll
  for (int sh = 0; sh < 2; ++sh) {
    int off = sh * 512;
    short8 kf0 = *(const short8*)(KsB + rb0 + off);
    short8 kf1 = *(const short8*)(KsB + rb1 + off);
    short8 kf2 = *(const short8*)(KsB + rb2 + off);
    short8 kf3 = *(const short8*)(KsB + rb3 + off);
    f32x4 dl0 = *(const f32x4*)&dl[sh * 32 + hi * 4];
    f32x4 dl1 = *(const f32x4*)&dl[sh * 32 + 8 + hi * 4];
    f32x4 dl2 = *(const f32x4*)&dl[sh * 32 + 16 + hi * 4];
    f32x4 dl3 = *(const f32x4*)&dl[sh * 32 + 24 + hi * 4];

    f32x16 scA, scB;
#pragma unroll
    for (int m = 0; m < 4; ++m) {
      scA[m] = dl0[m]; scA[4 + m] = dl1[m]; scA[8 + m] = dl2[m]; scA[12 + m] = dl3[m];
      scB[m] = dl0[m]; scB[4 + m] = dl1[m]; scB[8 + m] = dl2[m]; scB[12 + m] = dl3[m];
    }
    scA = __builtin_amdgcn_mfma_f32_32x32x16_bf16(kf0, qfA[0], scA, 0, 0, 0);
    scB = __builtin_amdgcn_mfma_f32_32x32x16_bf16(kf0, qfB[0], scB, 0, 0, 0);
    scA = __builtin_amdgcn_mfma_f32_32x32x16_bf16(kf1, qfA[1], scA, 0, 0, 0);
    scB = __builtin_amdgcn_mfma_f32_32x32x16_bf16(kf1, qfB[1], scB, 0, 0, 0);
    scA = __builtin_amdgcn_mfma_f32_32x32x16_bf16(kf2, qfA[2], scA, 0, 0, 0);
    scB = __builtin_amdgcn_mfma_f32_32x32x16_bf16(kf2, qfB[2], scB, 0, 0, 0);
    scA = __builtin_amdgcn_mfma_f32_32x32x16_bf16(kf3, qfA[3], scA, 0, 0, 0);
    scB = __builtin_amdgcn_mfma_f32_32x32x16_bf16(kf3, qfB[3], scB, 0, 0, 0);

    short8 pA0, pA1, pB0, pB1;
    lA += softpack(scA, pA0, pA1);
    lB += softpack(scB, pB0, pB1);

    int ra = (sh == 0) ? rb0 : rb2;
    int rbx = (sh == 0) ? rb1 : rb3;
    short8 vf = *(const short8*)(VsB + ra);
    oaA0 = __builtin_amdgcn_mfma_f32_32x32x16_bf16(vf, pA0, oaA0, 0, 0, 0);
    oaB0 = __builtin_amdgcn_mfma_f32_32x32x16_bf16(vf, pB0, oaB0, 0, 0, 0);
    vf = *(const short8*)(VsB + ra + 512);
    oaA1 = __builtin_amdgcn_mfma_f32_32x32x16_bf16(vf, pA0, oaA1, 0, 0, 0);
    oaB1 = __builtin_amdgcn_mfma_f32_32x32x16_bf16(vf, pB0, oaB1, 0, 0, 0);
    vf = *(const short8*)(VsB + rbx);
    oaA0 = __builtin_amdgcn_mfma_f32_32x32x16_bf16(vf, pA1, oaA0, 0, 0, 0);
    oaB0 = __builtin_amdgcn_mfma_f32_32x32x16_bf16(vf, pB1, oaB0, 0, 0, 0);
    vf = *(const short8*)(VsB + rbx + 512);
    oaA1 = __builtin_amdgcn_mfma_f32_32x32x16_bf16(vf, pA1, oaA1, 0, 0, 0);
    oaB1 = __builtin_amdgcn_mfma_f32_32x32x16_bf16(vf, pB1, oaB1, 0, 0, 0);
  }
}

// ---------------- flash attention: 64 q/wave, 2 TILES PER BARRIER -----------
// r23: paired-tile loop body. Tile b's QK chain is independent of tile a's
// softmax/PV -> cross-tile ILP fills dependency stalls (kernel was 57%
// stalled at 2 waves/SIMD). LDS 4-deep K/V buffers (65.5KB, still 2 blk/CU).
__global__ __launch_bounds__(256, 2)
void flash_attn(const u16* __restrict__ qh, const u16* __restrict__ kh,
                const u16* __restrict__ vt, const float* __restrict__ dl2g,
                u16* __restrict__ attn) {
  constexpr int S = 2048, E = 64;
  __shared__ __align__(16) u16 Ks[4][4096];
  __shared__ __align__(16) u16 Vs[4][4096];
  __shared__ __align__(16) float dls[4][64];

  int bh = blockIdx.x & 63, qb = blockIdx.x >> 6;  // same-head blocks share an XCD
  int b = bh >> 4, h = bh & 15;
  int tid = threadIdx.x, lane = tid & 63, w = tid >> 6;
  int l31 = lane & 31, hi = lane >> 5;
  int q0 = qb * 256 + w * 64;

  const u16* Kg = kh + (size_t)bh * S * E;
  const u16* Vg = vt + (size_t)bh * E * S;
  const float* Dg = dl2g + (size_t)b * S;

  // loop-invariant LDS addresses (bytes); chunk-major [c][row^c] layout (r7)
  int wbyte = (tid & 7) * 1024 + ((tid >> 3) ^ (tid & 7)) * 16;
  int rb0 = (hi) * 1024 + ((l31 ^ (hi)) * 16);
  int rb1 = (2 + hi) * 1024 + ((l31 ^ (2 + hi)) * 16);
  int rb2 = (4 + hi) * 1024 + ((l31 ^ (4 + hi)) * 16);
  int rb3 = (6 + hi) * 1024 + ((l31 ^ (6 + hi)) * 16);

  const u16* Qg = qh + ((size_t)bh * S + q0) * E;
  short8 qfA[4], qfB[4];  // B-frags: cols qA = q0+l31, qB = q0+32+l31
#pragma unroll
  for (int ec = 0; ec < 4; ++ec) {
    qfA[ec] = *(const short8*)&Qg[l31 * E + ec * 16 + hi * 8];
    qfB[ec] = *(const short8*)&Qg[(32 + l31) * E + ec * 16 + hi * 8];
  }

  float lA = 0.f, lB = 0.f;
  f32x16 oaA0, oaA1, oaB0, oaB1;
#pragma unroll
  for (int i = 0; i < 16; ++i) { oaA0[i] = 0.f; oaA1[i] = 0.f; oaB0[i] = 0.f; oaB1[i] = 0.f; }

  // prologue: stage tiles 0,1 via regs
  short8 ka0, ka1, kb0, kb1, va0, va1, vb0, vb1;
  {
    ka0 = *(const short8*)(Kg + (size_t)tid * 8);
    ka1 = *(const short8*)(Kg + (size_t)(256 + tid) * 8);
    kb0 = *(const short8*)(Kg + 4096 + (size_t)tid * 8);
    kb1 = *(const short8*)(Kg + 4096 + (size_t)(256 + tid) * 8);
    va0 = *(const short8*)(Vg + (size_t)(tid >> 3) * S + (tid & 7) * 8);
    va1 = *(const short8*)(Vg + (size_t)(32 + (tid >> 3)) * S + (tid & 7) * 8);
    vb0 = *(const short8*)(Vg + (size_t)(tid >> 3) * S + 64 + (tid & 7) * 8);
    vb1 = *(const short8*)(Vg + (size_t)(32 + (tid >> 3)) * S + 64 + (tid & 7) * 8);
  }
  if (tid < 32) gld_lds16(Dg + tid * 4, &dls[0][0]);  // fills dls[0] and dls[1]
  {
    *(short8*)((char*)&Ks[0][0] + wbyte) = ka0;
    *(short8*)((char*)&Ks[0][0] + wbyte + 512) = ka1;
    *(short8*)((char*)&Ks[1][0] + wbyte) = kb0;
    *(short8*)((char*)&Ks[1][0] + wbyte + 512) = kb1;
    *(short8*)((char*)&Vs[0][0] + wbyte) = va0;
    *(short8*)((char*)&Vs[0][0] + wbyte + 512) = va1;
    *(short8*)((char*)&Vs[1][0] + wbyte) = vb0;
    *(short8*)((char*)&Vs[1][0] + wbyte + 512) = vb1;
  }
  __syncthreads();

  for (int p = 0; p < 16; ++p) {  // 16 pairs of 64-s tiles
    int base = (p & 1) * 2, nb = base ^ 2;
    bool pf = (p < 15);
    if (pf) {  // issue next-pair loads early (latency hides under compute)
      int s1 = (p + 1) * 128;
      ka0 = *(const short8*)(Kg + (size_t)s1 * 64 + (size_t)tid * 8);
      ka1 = *(const short8*)(Kg + (size_t)s1 * 64 + (size_t)(256 + tid) * 8);
      kb0 = *(const short8*)(Kg + (size_t)(s1 + 64) * 64 + (size_t)tid * 8);
      kb1 = *(const short8*)(Kg + (size_t)(s1 + 64) * 64 + (size_t)(256 + tid) * 8);
      va0 = *(const short8*)(Vg + (size_t)(tid >> 3) * S + s1 + (tid & 7) * 8);
      va1 = *(const short8*)(Vg + (size_t)(32 + (tid >> 3)) * S + s1 + (tid & 7) * 8);
      vb0 = *(const short8*)(Vg + (size_t)(tid >> 3) * S + s1 + 64 + (tid & 7) * 8);
      vb1 = *(const short8*)(Vg + (size_t)(32 + (tid >> 3)) * S + s1 + 64 + (tid & 7) * 8);
      if (tid < 32) gld_lds16(Dg + s1 + tid * 4, &dls[nb][0]);  // dls[nb], dls[nb+1]
    }

    tile_compute((const char*)&Ks[base][0], (const char*)&Vs[base][0], &dls[base][0],
                 rb0, rb1, rb2, rb3, hi, qfA, qfB, oaA0, oaA1, oaB0, oaB1, lA, lB);
    tile_compute((const char*)&Ks[base + 1][0], (const char*)&Vs[base + 1][0], &dls[base + 1][0],
                 rb0, rb1, rb2, rb3, hi, qfA, qfB, oaA0, oaA1, oaB0, oaB1, lA, lB);

    if (pf) {  // write staged pair to other buffers (compiler inserts vmcnt)
      *(short8*)((char*)&Ks[nb][0] + wbyte) = ka0;
      *(short8*)((char*)&Ks[nb][0] + wbyte + 512) = ka1;
      *(short8*)((char*)&Ks[nb + 1][0] + wbyte) = kb0;
      *(short8*)((char*)&Ks[nb + 1][0] + wbyte + 512) = kb1;
      *(short8*)((char*)&Vs[nb][0] + wbyte) = va0;
      *(short8*)((char*)&Vs[nb][0] + wbyte + 512) = va1;
      *(short8*)((char*)&Vs[nb + 1][0] + wbyte) = vb0;
      *(short8*)((char*)&Vs[nb + 1][0] + wbyte + 512) = vb1;
    }
    __syncthreads();
  }

  // cross-half reduce (deferred) + normalize + store (B,L,H,E)
  lA += __shfl_xor(lA, 32);
  lB += __shfl_xor(lB, 32);
  float liA = 1.f / lA, liB = 1.f / lB;
  u16* OgA = attn + ((((size_t)b * 2048 + q0 + l31) * 16 + h) * 64);
  u16* OgB = attn + ((((size_t)b * 2048 + q0 + 32 + l31) * 16 + h) * 64);
#pragma unroll
  for (int g = 0; g < 4; ++g) {
    uint2v s0;
    s0[0] = cvtpk_bf16(oaA0[g * 4 + 0] * liA, oaA0[g * 4 + 1] * liA);
    s0[1] = cvtpk_bf16(oaA0[g * 4 + 2] * liA, oaA0[g * 4 + 3] * liA);
    *(uint2v*)&OgA[g * 8 + hi * 4] = s0;
    s0[0] = cvtpk_bf16(oaA1[g * 4 + 0] * liA, oaA1[g * 4 + 1] * liA);
    s0[1] = cvtpk_bf16(oaA1[g * 4 + 2] * liA, oaA1[g * 4 + 3] * liA);
    *(uint2v*)&OgA[32 + g * 8 + hi * 4] = s0;
    s0[0] = cvtpk_bf16(oaB0[g * 4 + 0] * liB, oaB0[g * 4 + 1] * liB);
    s0[1] = cvtpk_bf16(oaB0[g * 4 + 2] * liB, oaB0[g * 4 + 3] * liB);
    *(uint2v*)&OgB[g * 8 + hi * 4] = s0;
    s0[0] = cvtpk_bf16(oaB1[g * 4 + 0] * liB, oaB1[g * 4 + 1] * liB);
    s0[1] = cvtpk_bf16(oaB1[g * 4 + 2] * liB, oaB1[g * 4 + 3] * liB);
    *(uint2v*)&OgB[32 + g * 8 + hi * 4] = s0;
  }
}

// ---------------- launch ----------------
extern "C" void kernel_launch(void* const* d_in, const int* in_sizes, int n_in,
                              void* d_out, int out_size, void* d_ws, size_t ws_size,
                              hipStream_t stream) {
  const float* q = (const float*)d_in[0];
  const float* k = (const float*)d_in[1];
  const float* v = (const float*)d_in[2];
  const float* tau = (const float*)d_in[3];
  const float* delta = (const float*)d_in[4];
  const float* Wq = (const float*)d_in[5];
  const float* bq = (const float*)d_in[6];
  const float* Wk = (const float*)d_in[7];
  const float* bk = (const float*)d_in[8];
  const float* Wv = (const float*)d_in[9];
  const float* bv = (const float*)d_in[10];
  const float* Wo = (const float*)d_in[11];
  const float* bo = (const float*)d_in[12];

  const size_t SZ_ACT = (size_t)8192 * 1024 * 2;  // 16 MB bf16 activations
  const size_t SZ_W = (size_t)1024 * 1024 * 2;    // 2 MB bf16 weights
  char* p = (char*)d_ws;
  u16* qbf = (u16*)p; p += SZ_ACT;   // qbf|kbf|vbf contiguous: stacked A
  u16* kbf = (u16*)p; p += SZ_ACT;
  u16* vbf = (u16*)p; p += SZ_ACT;
  u16* wq = (u16*)p; p += SZ_W;      // wq|wk|wv|wo contiguous
  u16* wk = (u16*)p; p += SZ_W;
  u16* wv = (u16*)p; p += SZ_W;
  u16* wo = (u16*)p; p += SZ_W;
  float* dl2g = (float*)p; p += 8192 * 4;
  u16* qhb = (u16*)p; p += SZ_ACT;
  u16* khb = (u16*)p; p += SZ_ACT;
  u16* vtb = (u16*)p; p += SZ_ACT;
  u16* attn = qbf;  // reuse: qbf dead after QKV projection

  cvt_all<<<dim3(8192, 4), 256, 0, stream>>>(q, k, v, Wq, Wk, Wv, Wo, delta,
                                             qbf, kbf, vbf, wq, dl2g);
  gemm_qkv<<<1536, 256, 0, stream>>>(qbf, wq, bq, bk, bv, tau, qhb, khb, vtb);
  flash_attn<<<512, 256, 0, stream>>>(qhb, khb, vtb, dl2g, attn);
  gemm_out<<<512, 256, 0, stream>>>(attn, wo, bo, (float*)d_out);
}

// Round 24
// 189.347 us; speedup vs baseline: 1.2872x; 1.2872x over previous
//
#include <hip/hip_runtime.h>
#include <hip/hip_bf16.h>
#include <stdint.h>

typedef unsigned short u16;
typedef __attribute__((ext_vector_type(8))) short short8;   // 8 bf16 = 4 VGPR
typedef __attribute__((ext_vector_type(4))) short short4v;  // 8B
typedef __attribute__((ext_vector_type(4))) float f32x4;
typedef __attribute__((ext_vector_type(16))) float f32x16;
typedef __attribute__((ext_vector_type(2))) unsigned int uint2v;
typedef __attribute__((ext_vector_type(4))) unsigned int uint4v;

#define DEV static __device__ __forceinline__

DEV u16 f2bf(float f) {
  union { float f; unsigned u; } x; x.f = f;
  unsigned r = x.u + 0x7FFFu + ((x.u >> 16) & 1u);
  return (u16)(r >> 16);
}

DEV unsigned cvtpk_bf16(float a, float b) {  // mem order: {bf16(a), bf16(b)} (RNE)
  unsigned r;
  asm("v_cvt_pk_bf16_f32 %0, %1, %2" : "=v"(r) : "v"(a), "v"(b));
  return r;
}

// swaps a.hi32lanes <-> b.lo32lanes
DEV void pl32swap(unsigned& a, unsigned& b) {
  asm("v_permlane32_swap_b32 %0, %1" : "+v"(a), "+v"(b));
}

DEV void gld_lds16(const void* g, void* l) {
  __builtin_amdgcn_global_load_lds(
      (const __attribute__((address_space(1))) unsigned int*)(g),
      (__attribute__((address_space(3))) unsigned int*)(l),
      16, 0, 0);
}

// ---------------- merged fp32->bf16 converts + delta prescale ----------------
__global__ void cvt_all(const float* __restrict__ q, const float* __restrict__ k,
                        const float* __restrict__ v, const float* __restrict__ Wq,
                        const float* __restrict__ Wk, const float* __restrict__ Wv,
                        const float* __restrict__ Wo, const float* __restrict__ delta,
                        u16* __restrict__ qbf, u16* __restrict__ kbf,
                        u16* __restrict__ vbf, u16* __restrict__ wbase,
                        float* __restrict__ dl2g) {
  int tid = threadIdx.x;
  int y = blockIdx.y;
  if (y < 3) {
    int i = blockIdx.x * 256 + tid;
    const float* in = (y == 0) ? q : (y == 1) ? k : v;
    u16* out = (y == 0) ? qbf : (y == 1) ? kbf : vbf;
    float4 x = ((const float4*)in)[i];
    uint2v o;
    o[0] = cvtpk_bf16(x.x, x.y);
    o[1] = cvtpk_bf16(x.z, x.w);
    ((uint2v*)out)[i] = o;
    return;
  }
  int j = blockIdx.x * 256 + tid;
  if (j < 1048576) {  // weights: w uniform per block (262144 % 256 == 0)
    int w = j >> 18, jj = j & 262143;
    const float* in = (w == 0) ? Wq : (w == 1) ? Wk : (w == 2) ? Wv : Wo;
    u16* out = wbase + ((size_t)w << 20);
    float4 x = ((const float4*)in)[jj];
    uint2v o;
    o[0] = cvtpk_bf16(x.x, x.y);
    o[1] = cvtpk_bf16(x.z, x.w);
    ((uint2v*)out)[jj] = o;
  } else if (j < 1048576 + 2048) {  // delta prescale
    int jj = j - 1048576;
    constexpr float C = 0.125f * 1.44269504f;
    float4 x = ((const float4*)delta)[jj];
    f32x4 o = {x.x * C, x.y * C, x.z * C, x.w * C};
    ((f32x4*)dl2g)[jj] = o;
  }
}

// ---------------- fused QKV GEMM over stacked A (24576 x 1024) ----------------
// Q output pre-scaled by tau[b]*0.125*log2e. LDS-bounce epilogue (r22): C goes
// through a 136-padded LDS tile, then fully-coalesced 16B stores.
__global__ __launch_bounds__(256, 2)
void gemm_qkv(const u16* __restrict__ A, const u16* __restrict__ W,
              const float* __restrict__ bq, const float* __restrict__ bk,
              const float* __restrict__ bv, const float* __restrict__ tau,
              u16* __restrict__ qhb, u16* __restrict__ khb, u16* __restrict__ vtb) {
  constexpr int Nn = 1024, Kn = 1024;
  constexpr int BM = 128, BN = 128, BK = 64;
  __shared__ __align__(16) u16 smem[17408];
  u16* As = smem;
  u16* Bs = smem + 8192;
  constexpr int nbn = Nn / BN;            // 8
  constexpr int nwg = (24576 / BM) * nbn; // 1536
  int bid = blockIdx.x;
  int swz = (bid & 7) * (nwg >> 3) + (bid >> 3);
  int bm = (swz / nbn) * BM;
  int bn = (swz % nbn) * BN;
  int mat = bm >> 13;          // 0=Q 1=K 2=V
  int bml = bm & 8191;
  int tid = threadIdx.x;
  int lane = tid & 63, w = tid >> 6;
  int l15 = lane & 15, l4 = lane >> 4;
  int wm = (w >> 1) * 64, wn = (w & 1) * 64;
  int swl = (w << 6);

  f32x4 acc[4][4];
#pragma unroll
  for (int i = 0; i < 4; ++i)
#pragma unroll
    for (int j = 0; j < 4; ++j) acc[i][j] = (f32x4){0.f, 0.f, 0.f, 0.f};

  const u16* Ag = A + (size_t)bm * Kn;
  const u16* Bg = W + ((size_t)mat << 20) + (size_t)bn * Kn;

  for (int kt = 0; kt < Kn / BK; ++kt) {
    int k0 = kt * BK;
#pragma unroll
    for (int j = 0; j < 4; ++j) {
      int flat = j * 256 + tid;
      int row = flat >> 3, u = flat & 7;
      int gu = u ^ (row & 7);
      gld_lds16(Ag + (size_t)row * Kn + k0 + gu * 8, &As[(j * 256 + swl) * 8]);
    }
#pragma unroll
    for (int j = 0; j < 4; ++j) {
      int flat = j * 256 + tid;
      int row = flat >> 3, u = flat & 7;
      int gu = u ^ (row & 7);
      gld_lds16(Bg + (size_t)row * Kn + k0 + gu * 8, &Bs[(j * 256 + swl) * 8]);
    }
    __syncthreads();
#pragma unroll
    for (int ks = 0; ks < 2; ++ks) {
      short8 af[4], bfr[4];
#pragma unroll
      for (int i = 0; i < 4; ++i) {
        int ra = wm + i * 16 + l15;
        int ua = (ks * 4 + l4) ^ (ra & 7);
        af[i] = *(const short8*)&As[ra * 64 + ua * 8];
        int rb = wn + i * 16 + l15;
        int ub = (ks * 4 + l4) ^ (rb & 7);
        bfr[i] = *(const short8*)&Bs[rb * 64 + ub * 8];
      }
#pragma unroll
      for (int mi = 0; mi < 4; ++mi)
#pragma unroll
        for (int ni = 0; ni < 4; ++ni)
          acc[mi][ni] = __builtin_amdgcn_mfma_f32_16x16x32_bf16(af[mi], bfr[ni], acc[mi][ni], 0, 0, 0);
    }
    __syncthreads();
  }

  const float* bias = (mat == 0) ? bq : (mat == 1) ? bk : bv;
  float st2b = (mat == 0) ? tau[bml >> 11] * (0.125f * 1.44269504f) : 1.f;

  if (mat < 2) {
    u16* oQK = (mat == 0) ? qhb : khb;
#pragma unroll
    for (int ni = 0; ni < 4; ++ni) {
      int nl = wn + ni * 16 + l15;
      float bvl = bias[bn + nl];
#pragma unroll
      for (int mi = 0; mi < 4; ++mi) {
        int ml = wm + mi * 16 + l4 * 4;
        unsigned r0 = cvtpk_bf16((acc[mi][ni][0] + bvl) * st2b, (acc[mi][ni][1] + bvl) * st2b);
        unsigned r1 = cvtpk_bf16((acc[mi][ni][2] + bvl) * st2b, (acc[mi][ni][3] + bvl) * st2b);
        smem[(ml + 0) * 136 + nl] = (u16)r0;
        smem[(ml + 1) * 136 + nl] = (u16)(r0 >> 16);
        smem[(ml + 2) * 136 + nl] = (u16)r1;
        smem[(ml + 3) * 136 + nl] = (u16)(r1 >> 16);
      }
    }
    __syncthreads();
#pragma unroll
    for (int r = 0; r < 8; ++r) {
      int ml = r * 16 + (tid >> 4), seg = tid & 15;
      uint4v val = *(const uint4v*)&smem[ml * 136 + seg * 8];
      int m = bml + ml;
      int bb = m >> 11, l = m & 2047;
      int n = bn + seg * 8;
      int h = n >> 6, e = n & 63;
      *(uint4v*)&oQK[(((size_t)bb * 16 + h) * 2048 + l) * 64 + e] = val;
    }
  } else {
    // V: LDS transposed [n_local][m_local]; j gives 4 consecutive m -> b64 writes
#pragma unroll
    for (int ni = 0; ni < 4; ++ni) {
      int nl = wn + ni * 16 + l15;
      float bvl = bias[bn + nl];
#pragma unroll
      for (int mi = 0; mi < 4; ++mi) {
        int ml = wm + mi * 16 + l4 * 4;
        uint2v pk;
        pk[0] = cvtpk_bf16(acc[mi][ni][0] + bvl, acc[mi][ni][1] + bvl);
        pk[1] = cvtpk_bf16(acc[mi][ni][2] + bvl, acc[mi][ni][3] + bvl);
        *(uint2v*)&smem[nl * 136 + ml] = pk;
      }
    }
    __syncthreads();
#pragma unroll
    for (int r = 0; r < 8; ++r) {
      int nl = r * 16 + (tid >> 4), seg = tid & 15;
      uint4v val = *(const uint4v*)&smem[nl * 136 + seg * 8];
      int n = bn + nl;
      int h = n >> 6, e = n & 63;
      int bb = bml >> 11, s0 = (bml & 2047) + seg * 8;
      *(uint4v*)&vtb[(((size_t)bb * 16 + h) * 64 + e) * 2048 + s0] = val;
    }
  }
}

// ---------------- output GEMM: C = A(M,K) * Wo^T + bo, f32 out ----------------
__global__ __launch_bounds__(256, 2)
void gemm_out(const u16* __restrict__ A, const u16* __restrict__ Bt,
              const float* __restrict__ bias, float* __restrict__ out) {
  constexpr int Nn = 1024, Kn = 1024;
  constexpr int BM = 128, BN = 128, BK = 64;
  __shared__ __align__(16) u16 As[BM * BK];
  __shared__ __align__(16) u16 Bs[BN * BK];
  constexpr int nbn = Nn / BN;            // 8
  constexpr int nwg = (8192 / BM) * nbn;  // 512
  int bid = blockIdx.x;
  int swz = (bid & 7) * (nwg >> 3) + (bid >> 3);
  int bm = (swz / nbn) * BM;
  int bn = (swz % nbn) * BN;
  int tid = threadIdx.x;
  int lane = tid & 63, w = tid >> 6;
  int l15 = lane & 15, l4 = lane >> 4;
  int wm = (w >> 1) * 64, wn = (w & 1) * 64;
  int swl = (w << 6);

  f32x4 acc[4][4];
#pragma unroll
  for (int i = 0; i < 4; ++i)
#pragma unroll
    for (int j = 0; j < 4; ++j) acc[i][j] = (f32x4){0.f, 0.f, 0.f, 0.f};

  const u16* Ag = A + (size_t)bm * Kn;
  const u16* Bg = Bt + (size_t)bn * Kn;

  for (int kt = 0; kt < Kn / BK; ++kt) {
    int k0 = kt * BK;
#pragma unroll
    for (int j = 0; j < 4; ++j) {
      int flat = j * 256 + tid;
      int row = flat >> 3, u = flat & 7;
      int gu = u ^ (row & 7);
      gld_lds16(Ag + (size_t)row * Kn + k0 + gu * 8, &As[(j * 256 + swl) * 8]);
    }
#pragma unroll
    for (int j = 0; j < 4; ++j) {
      int flat = j * 256 + tid;
      int row = flat >> 3, u = flat & 7;
      int gu = u ^ (row & 7);
      gld_lds16(Bg + (size_t)row * Kn + k0 + gu * 8, &Bs[(j * 256 + swl) * 8]);
    }
    __syncthreads();
#pragma unroll
    for (int ks = 0; ks < 2; ++ks) {
      short8 af[4], bfr[4];
#pragma unroll
      for (int i = 0; i < 4; ++i) {
        int ra = wm + i * 16 + l15;
        int ua = (ks * 4 + l4) ^ (ra & 7);
        af[i] = *(const short8*)&As[ra * 64 + ua * 8];
        int rb = wn + i * 16 + l15;
        int ub = (ks * 4 + l4) ^ (rb & 7);
        bfr[i] = *(const short8*)&Bs[rb * 64 + ub * 8];
      }
#pragma unroll
      for (int mi = 0; mi < 4; ++mi)
#pragma unroll
        for (int ni = 0; ni < 4; ++ni)
          acc[mi][ni] = __builtin_amdgcn_mfma_f32_16x16x32_bf16(af[mi], bfr[ni], acc[mi][ni], 0, 0, 0);
    }
    __syncthreads();
  }

#pragma unroll
  for (int ni = 0; ni < 4; ++ni) {
    int n = bn + wn + ni * 16 + l15;
    float bvl = bias[n];
#pragma unroll
    for (int mi = 0; mi < 4; ++mi) {
      int m0 = bm + wm + mi * 16 + l4 * 4;
#pragma unroll
      for (int j = 0; j < 4; ++j)
        out[(size_t)(m0 + j) * Nn + n] = acc[mi][ni][j] + bvl;
    }
  }
}

// softmax + pack for one 32-s x 32-q subtile: sc already = logits in log2
// domain (st2 folded into Q, delta folded into MFMA C-init).
DEV float softpack(const f32x16 sc, short8& f0, short8& f1) {
  float pe[16];
#pragma unroll
  for (int i = 0; i < 16; ++i) pe[i] = __builtin_amdgcn_exp2f(sc[i]);
  float ps = 0.f;
#pragma unroll
  for (int i = 0; i < 16; i += 4) ps += (pe[i] + pe[i + 1]) + (pe[i + 2] + pe[i + 3]);
  unsigned a0 = cvtpk_bf16(pe[0], pe[1]), a1 = cvtpk_bf16(pe[2], pe[3]);
  unsigned b0 = cvtpk_bf16(pe[4], pe[5]), b1 = cvtpk_bf16(pe[6], pe[7]);
  pl32swap(a0, b0);
  pl32swap(a1, b1);
  f0 = __builtin_bit_cast(short8, (uint4v){a0, a1, b0, b1});
  unsigned c0 = cvtpk_bf16(pe[8], pe[9]), c1 = cvtpk_bf16(pe[10], pe[11]);
  unsigned d0 = cvtpk_bf16(pe[12], pe[13]), d1 = cvtpk_bf16(pe[14], pe[15]);
  pl32swap(c0, d0);
  pl32swap(c1, d1);
  f1 = __builtin_bit_cast(short8, (uint4v){c0, c1, d0, d1});
  return ps;
}

// ---------------- flash attention: 64 q/wave (r22 best: single tile) --------
__global__ __launch_bounds__(256, 2)
void flash_attn(const u16* __restrict__ qh, const u16* __restrict__ kh,
                const u16* __restrict__ vt, const float* __restrict__ dl2g,
                u16* __restrict__ attn) {
  constexpr int S = 2048, E = 64;
  __shared__ __align__(16) u16 Ks[2][4096];
  __shared__ __align__(16) u16 Vs[2][4096];
  __shared__ __align__(16) float dls[2][64];

  int bh = blockIdx.x & 63, qb = blockIdx.x >> 6;  // same-head blocks share an XCD
  int b = bh >> 4, h = bh & 15;
  int tid = threadIdx.x, lane = tid & 63, w = tid >> 6;
  int l31 = lane & 31, hi = lane >> 5;
  int q0 = qb * 256 + w * 64;

  const u16* Kg = kh + (size_t)bh * S * E;
  const u16* Vg = vt + (size_t)bh * E * S;
  const float* Dg = dl2g + (size_t)b * S;

  // loop-invariant LDS addresses (bytes); chunk-major [c][row^c] layout (r7)
  int wbyte = (tid & 7) * 1024 + ((tid >> 3) ^ (tid & 7)) * 16;
  int rb0 = (hi) * 1024 + ((l31 ^ (hi)) * 16);
  int rb1 = (2 + hi) * 1024 + ((l31 ^ (2 + hi)) * 16);
  int rb2 = (4 + hi) * 1024 + ((l31 ^ (4 + hi)) * 16);
  int rb3 = (6 + hi) * 1024 + ((l31 ^ (6 + hi)) * 16);

  const u16* Qg = qh + ((size_t)bh * S + q0) * E;
  short8 qfA[4], qfB[4];  // B-frags: cols qA = q0+l31, qB = q0+32+l31
#pragma unroll
  for (int ec = 0; ec < 4; ++ec) {
    qfA[ec] = *(const short8*)&Qg[l31 * E + ec * 16 + hi * 8];
    qfB[ec] = *(const short8*)&Qg[(32 + l31) * E + ec * 16 + hi * 8];
  }

  float lA = 0.f, lB = 0.f;
  f32x16 oaA0, oaA1, oaB0, oaB1;
#pragma unroll
  for (int i = 0; i < 16; ++i) { oaA0[i] = 0.f; oaA1[i] = 0.f; oaB0[i] = 0.f; oaB1[i] = 0.f; }

  // prologue: stage tile 0 via regs
  short8 k0, k1, v0, v1;
  {
    k0 = *(const short8*)(Kg + (size_t)tid * 8);
    k1 = *(const short8*)(Kg + (size_t)(256 + tid) * 8);
    v0 = *(const short8*)(Vg + (size_t)(tid >> 3) * S + (tid & 7) * 8);
    v1 = *(const short8*)(Vg + (size_t)(32 + (tid >> 3)) * S + (tid & 7) * 8);
  }
  if (tid < 16) gld_lds16(Dg + tid * 4, &dls[0][0]);
  {
    char* KsB = (char*)&Ks[0][0];
    char* VsB = (char*)&Vs[0][0];
    *(short8*)(KsB + wbyte) = k0;
    *(short8*)(KsB + wbyte + 512) = k1;
    *(short8*)(VsB + wbyte) = v0;
    *(short8*)(VsB + wbyte + 512) = v1;
  }
  __syncthreads();

  for (int t = 0; t < 32; ++t) {
    int cur = t & 1;
    bool pf = (t < 31);
    if (pf) {  // issue next-tile loads early (latency hides under compute)
      int s1 = (t + 1) * 64;
      k0 = *(const short8*)(Kg + (size_t)s1 * 64 + (size_t)tid * 8);
      k1 = *(const short8*)(Kg + (size_t)s1 * 64 + (size_t)(256 + tid) * 8);
      v0 = *(const short8*)(Vg + (size_t)(tid >> 3) * S + s1 + (tid & 7) * 8);
      v1 = *(const short8*)(Vg + (size_t)(32 + (tid >> 3)) * S + s1 + (tid & 7) * 8);
      if (tid < 16) gld_lds16(Dg + s1 + tid * 4, &dls[cur ^ 1][0]);
    }

    const char* KsB = (const char*)&Ks[cur][0];
    const char* VsB = (const char*)&Vs[cur][0];

#pragma unroll
    for (int sh = 0; sh < 2; ++sh) {  // s-half: rows sh*32 .. sh*32+31
      int off = sh * 512;             // +32 rows = +512B within chunk
      // held K-frags: each LDS read feeds A and B score MFMAs
      short8 kf0 = *(const short8*)(KsB + rb0 + off);
      short8 kf1 = *(const short8*)(KsB + rb1 + off);
      short8 kf2 = *(const short8*)(KsB + rb2 + off);
      short8 kf3 = *(const short8*)(KsB + rb3 + off);
      // delta C-init (reg g*4+m <-> row m+8g+4hi, matches f32x4 loads)
      f32x4 dl0 = *(const f32x4*)&dls[cur][sh * 32 + hi * 4];
      f32x4 dl1 = *(const f32x4*)&dls[cur][sh * 32 + 8 + hi * 4];
      f32x4 dl2 = *(const f32x4*)&dls[cur][sh * 32 + 16 + hi * 4];
      f32x4 dl3 = *(const f32x4*)&dls[cur][sh * 32 + 24 + hi * 4];

      f32x16 scA, scB;
#pragma unroll
      for (int m = 0; m < 4; ++m) {
        scA[m] = dl0[m]; scA[4 + m] = dl1[m]; scA[8 + m] = dl2[m]; scA[12 + m] = dl3[m];
        scB[m] = dl0[m]; scB[4 + m] = dl1[m]; scB[8 + m] = dl2[m]; scB[12 + m] = dl3[m];
      }
      scA = __builtin_amdgcn_mfma_f32_32x32x16_bf16(kf0, qfA[0], scA, 0, 0, 0);
      scB = __builtin_amdgcn_mfma_f32_32x32x16_bf16(kf0, qfB[0], scB, 0, 0, 0);
      scA = __builtin_amdgcn_mfma_f32_32x32x16_bf16(kf1, qfA[1], scA, 0, 0, 0);
      scB = __builtin_amdgcn_mfma_f32_32x32x16_bf16(kf1, qfB[1], scB, 0, 0, 0);
      scA = __builtin_amdgcn_mfma_f32_32x32x16_bf16(kf2, qfA[2], scA, 0, 0, 0);
      scB = __builtin_amdgcn_mfma_f32_32x32x16_bf16(kf2, qfB[2], scB, 0, 0, 0);
      scA = __builtin_amdgcn_mfma_f32_32x32x16_bf16(kf3, qfA[3], scA, 0, 0, 0);
      scB = __builtin_amdgcn_mfma_f32_32x32x16_bf16(kf3, qfB[3], scB, 0, 0, 0);

      short8 pA0, pA1, pB0, pB1;
      lA += softpack(scA, pA0, pA1);
      lB += softpack(scB, pB0, pB1);

      // PV: each V-frag read feeds A and B output MFMAs
      int ra = (sh == 0) ? rb0 : rb2;
      int rbx = (sh == 0) ? rb1 : rb3;
      {
        short8 vf = *(const short8*)(VsB + ra);
        oaA0 = __builtin_amdgcn_mfma_f32_32x32x16_bf16(vf, pA0, oaA0, 0, 0, 0);
        oaB0 = __builtin_amdgcn_mfma_f32_32x32x16_bf16(vf, pB0, oaB0, 0, 0, 0);
        vf = *(const short8*)(VsB + ra + 512);
        oaA1 = __builtin_amdgcn_mfma_f32_32x32x16_bf16(vf, pA0, oaA1, 0, 0, 0);
        oaB1 = __builtin_amdgcn_mfma_f32_32x32x16_bf16(vf, pB0, oaB1, 0, 0, 0);
        vf = *(const short8*)(VsB + rbx);
        oaA0 = __builtin_amdgcn_mfma_f32_32x32x16_bf16(vf, pA1, oaA0, 0, 0, 0);
        oaB0 = __builtin_amdgcn_mfma_f32_32x32x16_bf16(vf, pB1, oaB0, 0, 0, 0);
        vf = *(const short8*)(VsB + rbx + 512);
        oaA1 = __builtin_amdgcn_mfma_f32_32x32x16_bf16(vf, pA1, oaA1, 0, 0, 0);
        oaB1 = __builtin_amdgcn_mfma_f32_32x32x16_bf16(vf, pB1, oaB1, 0, 0, 0);
      }
    }

    if (pf) {  // write staged tile to other buffer (compiler inserts vmcnt)
      char* KsW = (char*)&Ks[cur ^ 1][0];
      char* VsW = (char*)&Vs[cur ^ 1][0];
      *(short8*)(KsW + wbyte) = k0;
      *(short8*)(KsW + wbyte + 512) = k1;
      *(short8*)(VsW + wbyte) = v0;
      *(short8*)(VsW + wbyte + 512) = v1;
    }
    __syncthreads();
  }

  // cross-half reduce (deferred) + normalize + store (B,L,H,E)
  lA += __shfl_xor(lA, 32);
  lB += __shfl_xor(lB, 32);
  float liA = 1.f / lA, liB = 1.f / lB;
  u16* OgA = attn + ((((size_t)b * 2048 + q0 + l31) * 16 + h) * 64);
  u16* OgB = attn + ((((size_t)b * 2048 + q0 + 32 + l31) * 16 + h) * 64);
#pragma unroll
  for (int g = 0; g < 4; ++g) {
    uint2v s0;
    s0[0] = cvtpk_bf16(oaA0[g * 4 + 0] * liA, oaA0[g * 4 + 1] * liA);
    s0[1] = cvtpk_bf16(oaA0[g * 4 + 2] * liA, oaA0[g * 4 + 3] * liA);
    *(uint2v*)&OgA[g * 8 + hi * 4] = s0;
    s0[0] = cvtpk_bf16(oaA1[g * 4 + 0] * liA, oaA1[g * 4 + 1] * liA);
    s0[1] = cvtpk_bf16(oaA1[g * 4 + 2] * liA, oaA1[g * 4 + 3] * liA);
    *(uint2v*)&OgA[32 + g * 8 + hi * 4] = s0;
    s0[0] = cvtpk_bf16(oaB0[g * 4 + 0] * liB, oaB0[g * 4 + 1] * liB);
    s0[1] = cvtpk_bf16(oaB0[g * 4 + 2] * liB, oaB0[g * 4 + 3] * liB);
    *(uint2v*)&OgB[g * 8 + hi * 4] = s0;
    s0[0] = cvtpk_bf16(oaB1[g * 4 + 0] * liB, oaB1[g * 4 + 1] * liB);
    s0[1] = cvtpk_bf16(oaB1[g * 4 + 2] * liB, oaB1[g * 4 + 3] * liB);
    *(uint2v*)&OgB[32 + g * 8 + hi * 4] = s0;
  }
}

// ---------------- launch ----------------
extern "C" void kernel_launch(void* const* d_in, const int* in_sizes, int n_in,
                              void* d_out, int out_size, void* d_ws, size_t ws_size,
                              hipStream_t stream) {
  const float* q = (const float*)d_in[0];
  const float* k = (const float*)d_in[1];
  const float* v = (const float*)d_in[2];
  const float* tau = (const float*)d_in[3];
  const float* delta = (const float*)d_in[4];
  const float* Wq = (const float*)d_in[5];
  const float* bq = (const float*)d_in[6];
  const float* Wk = (const float*)d_in[7];
  const float* bk = (const float*)d_in[8];
  const float* Wv = (const float*)d_in[9];
  const float* bv = (const float*)d_in[10];
  const float* Wo = (const float*)d_in[11];
  const float* bo = (const float*)d_in[12];

  const size_t SZ_ACT = (size_t)8192 * 1024 * 2;  // 16 MB bf16 activations
  const size_t SZ_W = (size_t)1024 * 1024 * 2;    // 2 MB bf16 weights
  char* p = (char*)d_ws;
  u16* qbf = (u16*)p; p += SZ_ACT;   // qbf|kbf|vbf contiguous: stacked A
  u16* kbf = (u16*)p; p += SZ_ACT;
  u16* vbf = (u16*)p; p += SZ_ACT;
  u16* wq = (u16*)p; p += SZ_W;      // wq|wk|wv|wo contiguous
  u16* wk = (u16*)p; p += SZ_W;
  u16* wv = (u16*)p; p += SZ_W;
  u16* wo = (u16*)p; p += SZ_W;
  float* dl2g = (float*)p; p += 8192 * 4;
  u16* qhb = (u16*)p; p += SZ_ACT;
  u16* khb = (u16*)p; p += SZ_ACT;
  u16* vtb = (u16*)p; p += SZ_ACT;
  u16* attn = qbf;  // reuse: qbf dead after QKV projection

  cvt_all<<<dim3(8192, 4), 256, 0, stream>>>(q, k, v, Wq, Wk, Wv, Wo, delta,
                                             qbf, kbf, vbf, wq, dl2g);
  gemm_qkv<<<1536, 256, 0, stream>>>(qbf, wq, bq, bk, bv, tau, qhb, khb, vtb);
  flash_attn<<<512, 256, 0, stream>>>(qhb, khb, vtb, dl2g, attn);
  gemm_out<<<512, 256, 0, stream>>>(attn, wo, bo, (float*)d_out);
}